// Round 2
// baseline (178.724 us; speedup 1.0000x reference)
//
#include <hip/hip_runtime.h>

// ReceptiveFieldNorm, N=16 C=3 H=W=768, fp32.
// Exactly 2 iterations, both subsampled to 256x256 (win k=51/p=25, then k=13/p=6).
// Down/up-sampling weights are the fixed 1/3-2/3 pattern; iteration 2 stats are
// derived algebraically at low-res; final pass fuses both affine maps.

#define N_B 16
#define CCH 3
#define HF 768
#define HL 256
#define SLICE (HL * HL)
#define TOT_L (N_B * SLICE)
#define EPSV 1e-3f

// ---------- subsample + per-pixel channel stats: u = mean_c x, v = mean_c x^2
__global__ void k_sub(const float* __restrict__ x, float* __restrict__ u,
                      float* __restrict__ v) {
  int idx = blockIdx.x * 256 + threadIdx.x;  // exact grid: TOT_L threads
  int j = idx & (HL - 1);
  int i = (idx >> 8) & (HL - 1);
  int n = idx >> 16;
  const float* xp = x + (size_t)n * CCH * HF * HF + (size_t)(3 * i + 1) * HF + (3 * j + 1);
  float c0 = xp[0], c1 = xp[HF * HF], c2 = xp[2 * HF * HF];
  u[idx] = (c0 + c1 + c2) * (1.f / 3.f);
  v[idx] = (c0 * c0 + c1 * c1 + c2 * c2) * (1.f / 3.f);
}

// ---------- horizontal box sum (zero-pad), two arrays, one row per block
template <int P>
__global__ void k_hbox(const float* __restrict__ in0, const float* __restrict__ in1,
                       float* __restrict__ out0, float* __restrict__ out1) {
  __shared__ float s0[HL], s1[HL];
  int row = blockIdx.x;  // n*256 + i
  int j = threadIdx.x;
  size_t base = (size_t)row * HL;
  s0[j] = in0[base + j];
  s1[j] = in1[base + j];
  __syncthreads();
  // inclusive prefix scan (Hillis-Steele)
  for (int off = 1; off < HL; off <<= 1) {
    float a0 = 0.f, a1 = 0.f;
    if (j >= off) { a0 = s0[j - off]; a1 = s1[j - off]; }
    __syncthreads();
    s0[j] += a0;
    s1[j] += a1;
    __syncthreads();
  }
  int hi = j + P; if (hi > HL - 1) hi = HL - 1;
  int lo = j - P - 1;
  float r0 = s0[hi], r1 = s1[hi];
  if (lo >= 0) { r0 -= s0[lo]; r1 -= s1[lo]; }
  out0[base + j] = r0;
  out1[base + j] = r1;
}

__device__ __forceinline__ int cntP(int i, int P) {
  int hi = i + P; if (hi > HL - 1) hi = HL - 1;
  int lo = i - P; if (lo < 0) lo = 0;
  return hi - lo + 1;
}

// ---------- vertical box sum (sliding window per column) + fused epilogue
// MODE 0: compute a = 1/std, b = -mean/std      (inputs are box(u), box(v))
// MODE 1: compute A = s0/M, B = s1/M            (map normalization)
// MODE 2: MODE 1 plus in-place update u,v -> iteration-2 stats
template <int P, int MODE>
__global__ void k_vbox(const float* __restrict__ in0, const float* __restrict__ in1,
                       float* __restrict__ out0, float* __restrict__ out1,
                       float* __restrict__ u, float* __restrict__ v) {
  const int NSEG = 16, SEGR = 16;
  int n = blockIdx.x / NSEG;
  int seg = blockIdx.x % NSEG;
  int j = threadIdx.x;  // column, 0..255
  const float* p0 = in0 + (size_t)n * SLICE;
  const float* p1 = in1 + (size_t)n * SLICE;
  int r0 = seg * SEGR;
  float s0 = 0.f, s1 = 0.f;
  int lead_lo = r0 - P; if (lead_lo < 0) lead_lo = 0;
  int lead_hi = r0 + P - 1; if (lead_hi > HL - 1) lead_hi = HL - 1;
  for (int r = lead_lo; r <= lead_hi; ++r) {
    s0 += p0[r * HL + j];
    s1 += p1[r * HL + j];
  }
  float cj = (float)cntP(j, P);
  for (int i = r0; i < r0 + SEGR; ++i) {
    int add = i + P;
    if (add <= HL - 1) { s0 += p0[add * HL + j]; s1 += p1[add * HL + j]; }
    float invM = 1.f / (cj * (float)cntP(i, P));
    size_t idx = (size_t)n * SLICE + (size_t)i * HL + j;
    if (MODE == 0) {
      float xm = s0 * invM;
      float x2m = s1 * invM;
      float var = x2m - xm * xm;
      if (var < 0.f) var = 0.f;
      var += EPSV;
      float inv = 1.f / sqrtf(var);
      out0[idx] = inv;
      out1[idx] = -xm * inv;
    } else {
      float A = s0 * invM, B = s1 * invM;
      out0[idx] = A;
      out1[idx] = B;
      if (MODE == 2) {
        float un = u[idx], vn = v[idx];
        u[idx] = A * un + B;
        v[idx] = A * A * vn + 2.f * A * B * un + B * B;
      }
    }
    int sub = i - P;
    if (sub >= 0) { s0 -= p0[sub * HL + j]; s1 -= p1[sub * HL + j]; }
  }
}

// ---------- bilinear upsample weights for 256 -> 768 (period-3 pattern)
__device__ __forceinline__ void upw(int q, int& i0, int& i1, float& w1) {
  int d = q / 3;
  int r = q - 3 * d;
  if (r == 1) { i0 = d; i1 = d; w1 = 0.f; }                                  // exact
  else if (r == 2) { i0 = d; i1 = d + 1; if (i1 > HL - 1) i1 = HL - 1; w1 = 1.f / 3.f; }
  else { i1 = d; i0 = d - 1; if (i0 < 0) i0 = 0; w1 = 2.f / 3.f; }
}

// ---------- fused output: out = A2up * (A1up * x + B1up) + B2up
__global__ __launch_bounds__(192) void k_final(
    const float* __restrict__ x, const float* __restrict__ A1m,
    const float* __restrict__ B1m, const float* __restrict__ A2m,
    const float* __restrict__ B2m, float* __restrict__ out) {
  __shared__ float ry[4][HL];  // y-interpolated map rows
  int nb = blockIdx.x;  // n*768 + y
  int y = nb % HF;
  int n = nb / HF;
  int t = threadIdx.x;
  int iy0, iy1;
  float wy1;
  upw(y, iy0, iy1, wy1);
  float wy0 = 1.f - wy1;
  size_t mb = (size_t)n * SLICE;
  for (int col = t; col < HL; col += 192) {
    ry[0][col] = wy0 * A1m[mb + (size_t)iy0 * HL + col] + wy1 * A1m[mb + (size_t)iy1 * HL + col];
    ry[1][col] = wy0 * B1m[mb + (size_t)iy0 * HL + col] + wy1 * B1m[mb + (size_t)iy1 * HL + col];
    ry[2][col] = wy0 * A2m[mb + (size_t)iy0 * HL + col] + wy1 * A2m[mb + (size_t)iy1 * HL + col];
    ry[3][col] = wy0 * B2m[mb + (size_t)iy0 * HL + col] + wy1 * B2m[mb + (size_t)iy1 * HL + col];
  }
  __syncthreads();
  float A1c[4], B1c[4], A2c[4], B2c[4];
#pragma unroll
  for (int e = 0; e < 4; ++e) {
    int q = 4 * t + e;
    int ix0, ix1;
    float wx1;
    upw(q, ix0, ix1, wx1);
    float wx0 = 1.f - wx1;
    A1c[e] = wx0 * ry[0][ix0] + wx1 * ry[0][ix1];
    B1c[e] = wx0 * ry[1][ix0] + wx1 * ry[1][ix1];
    A2c[e] = wx0 * ry[2][ix0] + wx1 * ry[2][ix1];
    B2c[e] = wx0 * ry[3][ix0] + wx1 * ry[3][ix1];
  }
  size_t rowbase = ((size_t)(n * CCH) * HF + y) * HF + 4 * t;
#pragma unroll
  for (int c = 0; c < CCH; ++c) {
    const float4 xin = *(const float4*)(x + rowbase + (size_t)c * HF * HF);
    float4 o;
    o.x = A2c[0] * (A1c[0] * xin.x + B1c[0]) + B2c[0];
    o.y = A2c[1] * (A1c[1] * xin.y + B1c[1]) + B2c[1];
    o.z = A2c[2] * (A1c[2] * xin.z + B1c[2]) + B2c[2];
    o.w = A2c[3] * (A1c[3] * xin.w + B1c[3]) + B2c[3];
    *(float4*)(out + rowbase + (size_t)c * HF * HF) = o;
  }
}

extern "C" void kernel_launch(void* const* d_in, const int* in_sizes, int n_in,
                              void* d_out, int out_size, void* d_ws, size_t ws_size,
                              hipStream_t stream) {
  const float* x = (const float*)d_in[0];
  float* out = (float*)d_out;
  const size_t S = (size_t)TOT_L;
  float* wsf = (float*)d_ws;
  float *u, *v, *t0, *t1, *a, *b, *A1, *B1, *A2, *B2;
  if (ws_size >= 10 * S * sizeof(float)) {
    u = wsf;     v = u + S;   t0 = v + S;  t1 = t0 + S; a = t1 + S;
    b = a + S;   A1 = b + S;  B1 = A1 + S; A2 = B1 + S; B2 = A2 + S;
  } else {
    // Maps k_final reads must stay in ws (16 MB); transient buffers can live
    // at the head of d_out (each is fully written before read, every call).
    A1 = wsf; B1 = A1 + S; A2 = B1 + S; B2 = A2 + S;
    u = out; v = u + S; t0 = v + S; t1 = t0 + S; a = t1 + S; b = a + S;
  }

  k_sub<<<TOT_L / 256, 256, 0, stream>>>(x, u, v);
  // iteration 1: win=51 -> k=51, p=25
  k_hbox<25><<<N_B * HL, HL, 0, stream>>>(u, v, t0, t1);
  k_vbox<25, 0><<<256, HL, 0, stream>>>(t0, t1, a, b, nullptr, nullptr);
  k_hbox<25><<<N_B * HL, HL, 0, stream>>>(a, b, t0, t1);
  k_vbox<25, 2><<<256, HL, 0, stream>>>(t0, t1, A1, B1, u, v);
  // iteration 2: win=12 -> k=13, p=6 (stats derived in-place by MODE 2 above)
  k_hbox<6><<<N_B * HL, HL, 0, stream>>>(u, v, t0, t1);
  k_vbox<6, 0><<<256, HL, 0, stream>>>(t0, t1, a, b, nullptr, nullptr);
  k_hbox<6><<<N_B * HL, HL, 0, stream>>>(a, b, t0, t1);
  k_vbox<6, 1><<<256, HL, 0, stream>>>(t0, t1, A2, B2, nullptr, nullptr);
  // fused final full-res pass
  k_final<<<N_B * HF, 192, 0, stream>>>(x, A1, B1, A2, B2, out);
}

// Round 5
// 146.162 us; speedup vs baseline: 1.2228x; 1.2228x over previous
//
#include <hip/hip_runtime.h>

// ReceptiveFieldNorm, N=16 C=3 H=W=768, fp32. Two iterations (win 51 then 13
// at 256x256). Horizontal box-scans fused into their producing kernels
// (one row per thread-block row-pass, shfl-based scan). 6 dispatches total.

#define N_B 16
#define CCH 3
#define HF 768
#define HL 256
#define SLICE (HL * HL)
#define TOT_L (N_B * SLICE)
#define EPSV 1e-3f
#define SEGR 8
#define NSEG (HL / SEGR)

__device__ __forceinline__ int cnt(int i, int P) {
  int hi = i + P; if (hi > HL - 1) hi = HL - 1;
  int lo = i - P; if (lo < 0) lo = 0;
  return hi - lo + 1;
}

// Dual zero-padded horizontal box-sum of one row held one-element-per-thread.
// Wave shfl scan + cross-wave offsets via LDS. 3 syncthreads per call.
template <int P>
__device__ __forceinline__ void hbox2(float a, float b, int j,
                                      float* s0, float* s1, float* wt,
                                      float& ra, float& rb) {
  int lane = j & 63, w = j >> 6;
  __syncthreads();  // protect LDS reuse across calls
#pragma unroll
  for (int d = 1; d < 64; d <<= 1) {
    float ta = __shfl_up(a, (unsigned)d);
    float tb = __shfl_up(b, (unsigned)d);
    if (lane >= d) { a += ta; b += tb; }
  }
  if (lane == 63) { wt[w] = a; wt[4 + w] = b; }
  __syncthreads();
  float offa = 0.f, offb = 0.f;
  for (int ww = 0; ww < w; ++ww) { offa += wt[ww]; offb += wt[4 + ww]; }
  s0[j] = a + offa;
  s1[j] = b + offb;
  __syncthreads();
  int hi = j + P; if (hi > HL - 1) hi = HL - 1;
  int lo = j - P - 1;
  ra = s0[hi]; rb = s1[hi];
  if (lo >= 0) { ra -= s0[lo]; rb -= s1[lo]; }
}

// ---------- k1: subsample + channel stats + h-scan(P=25); also store raw u,v
__global__ __launch_bounds__(HL) void k1(const float* __restrict__ x,
    float* __restrict__ u, float* __restrict__ v,
    float* __restrict__ t0, float* __restrict__ t1) {
  __shared__ float s0[HL], s1[HL], wt[8];
  int row = blockIdx.x;  // n*HL + i
  int n = row >> 8, i = row & (HL - 1);
  int j = threadIdx.x;
  const float* xp = x + (size_t)n * CCH * HF * HF + (size_t)(3 * i + 1) * HF + (3 * j + 1);
  float c0 = xp[0], c1 = xp[HF * HF], c2 = xp[2 * HF * HF];
  float uu = (c0 + c1 + c2) * (1.f / 3.f);
  float vv = (c0 * c0 + c1 * c1 + c2 * c2) * (1.f / 3.f);
  size_t base = (size_t)row * HL;
  u[base + j] = uu;
  v[base + j] = vv;
  float ra, rb;
  hbox2<25>(uu, vv, j, s0, s1, wt, ra, rb);
  t0[base + j] = ra;
  t1[base + j] = rb;
}

// ---------- vertical sliding-window box (radius P) + fused epilogue/h-scan(P2)
// MODE 0: (box(u),box(v)) -> a=1/std, b=-mean/std; h-scan P2; write out0,out1
// MODE 2: -> A,B maps; iter-2 stats u2=A*u+B, v2=A^2 v+2AB u+B^2; h-scan P2 -> out
// MODE 1: -> A,B maps only
template <int P, int MODE, int P2>
__global__ __launch_bounds__(HL) void k_vs(const float* __restrict__ in0,
    const float* __restrict__ in1, float* __restrict__ out0,
    float* __restrict__ out1, const float* __restrict__ u,
    const float* __restrict__ v, float* __restrict__ m0,
    float* __restrict__ m1) {
  __shared__ float s0[HL], s1[HL], wt[8];
  int n = blockIdx.x / NSEG, seg = blockIdx.x % NSEG;
  int j = threadIdx.x;
  const float* p0 = in0 + (size_t)n * SLICE;
  const float* p1 = in1 + (size_t)n * SLICE;
  int r0 = seg * SEGR;
  float a0 = 0.f, a1 = 0.f;
  int llo = r0 - P; if (llo < 0) llo = 0;
  int lhi = r0 + P - 1; if (lhi > HL - 1) lhi = HL - 1;
  for (int r = llo; r <= lhi; ++r) { a0 += p0[r * HL + j]; a1 += p1[r * HL + j]; }
  float cj = (float)cnt(j, P);
  for (int i = r0; i < r0 + SEGR; ++i) {
    int add = i + P;
    if (add <= HL - 1) { a0 += p0[add * HL + j]; a1 += p1[add * HL + j]; }
    float invM = 1.f / (cj * (float)cnt(i, P));
    size_t idx = (size_t)n * SLICE + (size_t)i * HL + j;
    float o0 = 0.f, o1 = 0.f;
    if constexpr (MODE == 0) {
      float xm = a0 * invM, x2m = a1 * invM;
      float var = x2m - xm * xm; if (var < 0.f) var = 0.f;
      float inv = 1.f / sqrtf(var + EPSV);
      o0 = inv; o1 = -xm * inv;
    } else {
      float A = a0 * invM, B = a1 * invM;
      m0[idx] = A; m1[idx] = B;
      if constexpr (MODE == 2) {
        float un = u[idx], vn = v[idx];
        o0 = A * un + B;
        o1 = A * A * vn + 2.f * A * B * un + B * B;
      }
    }
    if constexpr (MODE != 1) {
      float ra, rb;
      hbox2<P2>(o0, o1, j, s0, s1, wt, ra, rb);
      out0[idx] = ra;
      out1[idx] = rb;
    }
    int sub = i - P;
    if (sub >= 0) { a0 -= p0[sub * HL + j]; a1 -= p1[sub * HL + j]; }
  }
}

// ---------- bilinear upsample weights for 256 -> 768 (period-3 pattern)
__device__ __forceinline__ void upw(int q, int& i0, int& i1, float& w1) {
  int d = q / 3;
  int r = q - 3 * d;
  if (r == 1) { i0 = d; i1 = d; w1 = 0.f; }
  else if (r == 2) { i0 = d; i1 = d + 1; if (i1 > HL - 1) i1 = HL - 1; w1 = 1.f / 3.f; }
  else { i1 = d; i0 = d - 1; if (i0 < 0) i0 = 0; w1 = 2.f / 3.f; }
}

// ---------- fused output: out = A2up * (A1up * x + B1up) + B2up
__global__ __launch_bounds__(192) void k_final(
    const float* __restrict__ x, const float* __restrict__ A1m,
    const float* __restrict__ B1m, const float* __restrict__ A2m,
    const float* __restrict__ B2m, float* __restrict__ out) {
  __shared__ float ry[4][HL];
  int nb = blockIdx.x;  // n*768 + y
  int y = nb % HF;
  int n = nb / HF;
  int t = threadIdx.x;
  int iy0, iy1;
  float wy1;
  upw(y, iy0, iy1, wy1);
  float wy0 = 1.f - wy1;
  size_t mb = (size_t)n * SLICE;
  for (int col = t; col < HL; col += 192) {
    ry[0][col] = wy0 * A1m[mb + (size_t)iy0 * HL + col] + wy1 * A1m[mb + (size_t)iy1 * HL + col];
    ry[1][col] = wy0 * B1m[mb + (size_t)iy0 * HL + col] + wy1 * B1m[mb + (size_t)iy1 * HL + col];
    ry[2][col] = wy0 * A2m[mb + (size_t)iy0 * HL + col] + wy1 * A2m[mb + (size_t)iy1 * HL + col];
    ry[3][col] = wy0 * B2m[mb + (size_t)iy0 * HL + col] + wy1 * B2m[mb + (size_t)iy1 * HL + col];
  }
  __syncthreads();
  float A1c[4], B1c[4], A2c[4], B2c[4];
#pragma unroll
  for (int e = 0; e < 4; ++e) {
    int q = 4 * t + e;
    int ix0, ix1;
    float wx1;
    upw(q, ix0, ix1, wx1);
    float wx0 = 1.f - wx1;
    A1c[e] = wx0 * ry[0][ix0] + wx1 * ry[0][ix1];
    B1c[e] = wx0 * ry[1][ix0] + wx1 * ry[1][ix1];
    A2c[e] = wx0 * ry[2][ix0] + wx1 * ry[2][ix1];
    B2c[e] = wx0 * ry[3][ix0] + wx1 * ry[3][ix1];
  }
  size_t rowbase = ((size_t)(n * CCH) * HF + y) * HF + 4 * t;
#pragma unroll
  for (int c = 0; c < CCH; ++c) {
    const float4 xin = *(const float4*)(x + rowbase + (size_t)c * HF * HF);
    float4 o;
    o.x = A2c[0] * (A1c[0] * xin.x + B1c[0]) + B2c[0];
    o.y = A2c[1] * (A1c[1] * xin.y + B1c[1]) + B2c[1];
    o.z = A2c[2] * (A1c[2] * xin.z + B1c[2]) + B2c[2];
    o.w = A2c[3] * (A1c[3] * xin.w + B1c[3]) + B2c[3];
    *(float4*)(out + rowbase + (size_t)c * HF * HF) = o;
  }
}

extern "C" void kernel_launch(void* const* d_in, const int* in_sizes, int n_in,
                              void* d_out, int out_size, void* d_ws, size_t ws_size,
                              hipStream_t stream) {
  const float* x = (const float*)d_in[0];
  float* out = (float*)d_out;
  const size_t S = (size_t)TOT_L;
  float* wsf = (float*)d_ws;
  float *u, *v, *t0, *t1, *t2, *t3, *A1, *B1, *A2, *B2;
  if (ws_size >= 10 * S * sizeof(float)) {
    u = wsf;      v = u + S;   t0 = v + S;   t1 = t0 + S;  t2 = t1 + S;
    t3 = t2 + S;  A1 = t3 + S; B1 = A1 + S;  A2 = B1 + S;  B2 = A2 + S;
  } else {
    // Maps k_final reads stay in ws (16 MB); transients live at the head of
    // d_out (each fully written before read, every call).
    A1 = wsf; B1 = A1 + S; A2 = B1 + S; B2 = A2 + S;
    u = out; v = u + S; t0 = v + S; t1 = t0 + S; t2 = t1 + S; t3 = t2 + S;
  }

  k1<<<N_B * HL, HL, 0, stream>>>(x, u, v, t0, t1);
  k_vs<25, 0, 25><<<N_B * NSEG, HL, 0, stream>>>(t0, t1, t2, t3, nullptr, nullptr, nullptr, nullptr);
  k_vs<25, 2, 6><<<N_B * NSEG, HL, 0, stream>>>(t2, t3, t0, t1, u, v, A1, B1);
  k_vs<6, 0, 6><<<N_B * NSEG, HL, 0, stream>>>(t0, t1, t2, t3, nullptr, nullptr, nullptr, nullptr);
  k_vs<6, 1, 0><<<N_B * NSEG, HL, 0, stream>>>(t2, t3, nullptr, nullptr, nullptr, nullptr, A2, B2);
  k_final<<<N_B * HF, 192, 0, stream>>>(x, A1, B1, A2, B2, out);
}